// Round 10
// baseline (137.817 us; speedup 1.0000x reference)
//
#include <hip/hip_runtime.h>
#include <math.h>

#define GRID_G 60
#define GRID_GG 3600
#define BPB 4   // boxes per block; 256 thr; ~32 KB LDS -> 4 independent blocks/CU

// ---------- width-64 butterfly reductions ----------
__device__ __forceinline__ float wredsum(float v){
  #pragma unroll
  for (int m = 32; m; m >>= 1) v += __shfl_xor(v, m, 64);
  return v;
}
__device__ __forceinline__ float wredmax(float v){
  #pragma unroll
  for (int m = 32; m; m >>= 1) v = fmaxf(v, __shfl_xor(v, m, 64));
  return v;
}
__device__ __forceinline__ float wredmin(float v){
  #pragma unroll
  for (int m = 32; m; m >>= 1) v = fminf(v, __shfl_xor(v, m, 64));
  return v;
}
__device__ __forceinline__ float frcp(float x){ return __builtin_amdgcn_rcpf(x); }
__device__ __forceinline__ float fsig(float x){ return frcp(1.0f + __expf(-x)); }
__device__ __forceinline__ float ftanh(float x){ return 1.0f - 2.0f*frcp(1.0f + __expf(2.0f*x)); }

__device__ __forceinline__ unsigned short f2bf(float x){
  unsigned int u = __float_as_uint(x);
  return (unsigned short)((u + 0x7fffu + ((u >> 16) & 1u)) >> 16);   // RNE
}
__device__ __forceinline__ float bf_lo(unsigned int u){ return __uint_as_float(u << 16); }
__device__ __forceinline__ float bf_hi(unsigned int u){ return __uint_as_float(u & 0xffff0000u); }

// ---------- kernel 1: weight transpose to K-major BF16 (1 uint = 2 rows) -----
__global__ __launch_bounds__(256) void transpose_kernel(
    const float* __restrict__ W_ih,
    const float* __restrict__ W_p1, const float* __restrict__ W_s1,
    const float* __restrict__ W_c1,
    unsigned int* __restrict__ wt_ih2, unsigned int* __restrict__ wt_h2)
{
  const int i = blockIdx.x * 256 + threadIdx.x;
  if (i < 18432) {                        // 96*384/2 uints
    const int e = i * 2;
    const int k = e / 384, r0 = e % 384;  // r0 even
    const int row0 = (r0     < 128) ? r0     : r0 + 128;
    const int row1 = (r0 + 1 < 128) ? r0 + 1 : r0 + 1 + 128;
    const unsigned int lo = f2bf(W_ih[row0 * 96 + k]);
    const unsigned int hi = f2bf(W_ih[row1 * 96 + k]);
    wt_ih2[i] = lo | (hi << 16);
  } else if (i < 18432 + 12288) {         // 128*192/2 uints
    const int j = i - 18432;
    const int e = j * 2;
    const int k = e / 192, r0 = e % 192;
    const float* W = (r0 < 64) ? W_p1 : (r0 < 128) ? W_s1 : W_c1;
    const unsigned int lo = f2bf(W[((r0    ) & 63) * 128 + k]);
    const unsigned int hi = f2bf(W[((r0 + 1) & 63) * 128 + k]);
    wt_h2[j] = lo | (hi << 16);
  }
}

// ---------- kernel 2: fused tracker; bf16 K-major stream; 4 blocks/CU ---------
__global__ __launch_bounds__(256) void tracker_kernel(
    const float* __restrict__ mv,        // (2,60,60)
    const float* __restrict__ boxes,     // (N,4)
    const float* __restrict__ W_stats, const float* __restrict__ b_stats,
    const float* __restrict__ g_stats, const float* __restrict__ be_stats,
    const float* __restrict__ W_b1,  const float* __restrict__ b_b1,
    const float* __restrict__ g_b1,  const float* __restrict__ be_b1,
    const float* __restrict__ W_b2,  const float* __restrict__ b_b2,
    const float* __restrict__ g_b2,  const float* __restrict__ be_b2,
    const unsigned int* __restrict__ wt_ih2, // bf16 K-major [96][384]
    const float* __restrict__ b_ih,  const float* __restrict__ b_hh,
    const unsigned int* __restrict__ wt_h2,  // bf16 K-major [128][192]
    const float* __restrict__ b_p1,  const float* __restrict__ W_p2, const float* __restrict__ b_p2,
    const float* __restrict__ b_s1,  const float* __restrict__ W_s2, const float* __restrict__ b_s2,
    const float* __restrict__ b_c1,  const float* __restrict__ W_c2, const float* __restrict__ b_c2,
    float* __restrict__ out, int N)
{
  __shared__ __align__(16) float x_lds[BPB][96];   // [mv_feat(64) | box_feat(32)]
  __shared__ __align__(16) float sP[4][BPB][384];  // GEMV partials (24.6 KB, reused)
  __shared__ __align__(16) float h_lds[BPB][128];  // LSTM hidden
  __shared__ __align__(16) float h1_lds[BPB][32];
  __shared__ float u_lds[3*BPB][65];               // head hidden, +1 pad
  __shared__ float res_lds[BPB][5];

  const int tid  = threadIdx.x;
  const int base = blockIdx.x * BPB;

  // ---- P2a/P3 thread identities + pre-barrier weight prefetch (chunk 0) ----
  const int o2 = tid % 48, s2 = tid / 48;   // P2a: rows 8o2..+7, k in [24s2,24s2+24)
  const int o3 = tid % 24, s3 = tid / 24;   // P3:  rows 8o3..+7, k in [16s3,16s3+16)
  uint4 Wpre2[4];
  if (tid < 192) {
    const int k0 = s2 * 24;
    #pragma unroll
    for (int kk = 0; kk < 4; ++kk)
      Wpre2[kk] = *(const uint4*)(wt_ih2 + ((size_t)(k0 + kk) * 384 + 8*o2) / 2);
  }

  // ========== Phase 1: one FULL wave per box, 4 boxes parallel ================
  {
    const int b    = tid >> 6;
    const int lane = tid & 63;
    const int l32  = lane & 31;
    int gb = base + b; if (gb >= N) gb = N - 1;   // clamp: dup work, writes guarded
    const float4 bx = ((const float4*)boxes)[gb];
    const float bn0 = fminf(fmaxf(bx.x * (1.0f/960.0f), 0.f), 1.f);
    const float bn1 = fminf(fmaxf(bx.y * (1.0f/960.0f), 0.f), 1.f);
    const float bn2 = fminf(fmaxf(bx.z * (1.0f/960.0f), 0.f), 1.f);
    const float bn3 = fminf(fmaxf(bx.w * (1.0f/960.0f), 0.f), 1.f);

    int x1 = (int)floorf(bn0 * 60.f); x1 = min(max(x1, 0), 59);
    int y1 = (int)floorf(bn1 * 60.f); y1 = min(max(y1, 0), 59);
    int x2 = (int)ceilf (bn2 * 60.f); x2 = min(max(x2, x1 + 1), 60);
    int y2 = (int)ceilf (bn3 * 60.f); y2 = min(max(y2, y1 + 1), 60);
    const int w = x2 - x1, hh = y2 - y1;
    const int cnt = w * hh;              // <= ~121 -> <=2 gather iterations
    const float rw = 1.0f / (float)w;

    float s0=0.f, s1=0.f, q0=0.f, q1=0.f;
    float hi0=-1e30f, hi1=-1e30f, lo0=1e30f, lo1=1e30f;
    for (int c = lane; c < cnt; c += 64) {
      const int yy = (int)(((float)c + 0.5f) * rw);   // exact floor(c/w) here
      const int xx = c - yy * w;
      const int idx = (y1 + yy) * GRID_G + (x1 + xx);
      const float m0 = mv[idx];
      const float m1 = mv[GRID_GG + idx];
      s0 += m0; q0 += m0*m0; hi0 = fmaxf(hi0, m0); lo0 = fminf(lo0, m0);
      s1 += m1; q1 += m1*m1; hi1 = fmaxf(hi1, m1); lo1 = fminf(lo1, m1);
    }
    s0 = wredsum(s0); q0 = wredsum(q0); hi0 = wredmax(hi0); lo0 = wredmin(lo0);
    s1 = wredsum(s1); q1 = wredsum(q1); hi1 = wredmax(hi1); lo1 = wredmin(lo1);
    const float inv = frcp((float)cnt);
    float st[6];
    st[0] = s0 * inv;
    st[1] = s1 * inv;
    st[2] = sqrtf(fmaxf(q0 * inv - st[0]*st[0], 0.f));
    st[3] = sqrtf(fmaxf(q1 * inv - st[1]*st[1], 0.f));
    st[4] = hi0 - lo0;
    st[5] = hi1 - lo1;

    // mv_feat (64) + LN64 + relu
    {
      const float* Wr = W_stats + lane * 6;
      float v = b_stats[lane];
      #pragma unroll
      for (int k = 0; k < 6; ++k) v = fmaf(st[k], Wr[k], v);
      const float mu  = wredsum(v)   * (1.0f/64.0f);
      const float var = wredsum(v*v) * (1.0f/64.0f) - mu*mu;
      x_lds[b][lane] = fmaxf((v - mu) * rsqrtf(var + 1e-5f) * g_stats[lane] + be_stats[lane], 0.f);
    }

    // h1 (32) + LN32 (upper half-wave duplicates, masked from reduction)
    {
      const float* Wr = W_b1 + l32 * 4;
      const float v = b_b1[l32] + bn0*Wr[0] + bn1*Wr[1] + bn2*Wr[2] + bn3*Wr[3];
      const float cv  = (lane < 32) ? v   : 0.f;
      const float cq  = (lane < 32) ? v*v : 0.f;
      const float mu  = wredsum(cv) * (1.0f/32.0f);
      const float var = wredsum(cq) * (1.0f/32.0f) - mu*mu;
      const float h1v = fmaxf((v - mu) * rsqrtf(var + 1e-5f) * g_b1[l32] + be_b1[l32], 0.f);
      if (lane < 32) h1_lds[b][l32] = h1v;
    }
    __threadfence_block();   // producer/consumer = same wave

    // box_feat (32) + LN32 + relu
    {
      const float* Wr = W_b2 + l32 * 32;
      float v = b_b2[l32];
      #pragma unroll
      for (int kk = 0; kk < 8; ++kk) {
        const float4 hv = *(const float4*)(&h1_lds[b][kk * 4]);  // broadcast
        const float4 wv = *(const float4*)(&Wr[kk * 4]);
        v = fmaf(wv.x,hv.x, fmaf(wv.y,hv.y, fmaf(wv.z,hv.z, fmaf(wv.w,hv.w, v))));
      }
      const float cv  = (lane < 32) ? v   : 0.f;
      const float cq  = (lane < 32) ? v*v : 0.f;
      const float mu  = wredsum(cv) * (1.0f/32.0f);
      const float var = wredsum(cq) * (1.0f/32.0f) - mu*mu;
      const float y = fmaxf((v - mu) * rsqrtf(var + 1e-5f) * g_b2[l32] + be_b2[l32], 0.f);
      if (lane < 32) x_lds[b][64 + l32] = y;
    }
  }
  __syncthreads();

  // ========== Phase 2a: gate pre-acts. Thread = (row-OCTET o2<48, k-qtr s2<4) ==
  uint4 Wpre3[4];   // P3 chunk-0 prefetch, issued at end of P2a
  if (tid < 192) {
    const int k0 = s2 * 24;
    float acc[8][BPB];
    #pragma unroll
    for (int j = 0; j < 8; ++j)
      #pragma unroll
      for (int b = 0; b < BPB; ++b) acc[j][b] = 0.f;
    #pragma unroll
    for (int k4 = 0; k4 < 6; ++k4) {
      const int kb = k0 + 4*k4;
      uint4 W[4];
      if (k4 == 0) {
        #pragma unroll
        for (int kk = 0; kk < 4; ++kk) W[kk] = Wpre2[kk];
      } else {
        #pragma unroll
        for (int kk = 0; kk < 4; ++kk)
          W[kk] = *(const uint4*)(wt_ih2 + ((size_t)(kb + kk) * 384 + 8*o2) / 2);
      }
      float4 xv[BPB];
      #pragma unroll
      for (int b = 0; b < BPB; ++b) xv[b] = *(const float4*)(&x_lds[b][kb]);  // broadcast
      #pragma unroll
      for (int kk = 0; kk < 4; ++kk) {
        const float w0 = bf_lo(W[kk].x), w1 = bf_hi(W[kk].x);
        const float w2 = bf_lo(W[kk].y), w3 = bf_hi(W[kk].y);
        const float w4 = bf_lo(W[kk].z), w5 = bf_hi(W[kk].z);
        const float w6 = bf_lo(W[kk].w), w7 = bf_hi(W[kk].w);
        #pragma unroll
        for (int b = 0; b < BPB; ++b) {
          const float xc = (kk == 0) ? xv[b].x : (kk == 1) ? xv[b].y : (kk == 2) ? xv[b].z : xv[b].w;
          acc[0][b] = fmaf(w0, xc, acc[0][b]);
          acc[1][b] = fmaf(w1, xc, acc[1][b]);
          acc[2][b] = fmaf(w2, xc, acc[2][b]);
          acc[3][b] = fmaf(w3, xc, acc[3][b]);
          acc[4][b] = fmaf(w4, xc, acc[4][b]);
          acc[5][b] = fmaf(w5, xc, acc[5][b]);
          acc[6][b] = fmaf(w6, xc, acc[6][b]);
          acc[7][b] = fmaf(w7, xc, acc[7][b]);
        }
      }
    }
    // prefetch P3 chunk 0 while partial stores + barrier drain
    {
      const int k0h = s3 * 16;
      #pragma unroll
      for (int kk = 0; kk < 4; ++kk)
        Wpre3[kk] = *(const uint4*)(wt_h2 + ((size_t)(k0h + kk) * 192 + 8*o3) / 2);
    }
    #pragma unroll
    for (int b = 0; b < BPB; ++b) {
      float4 v0; v0.x = acc[0][b]; v0.y = acc[1][b]; v0.z = acc[2][b]; v0.w = acc[3][b];
      float4 v1; v1.x = acc[4][b]; v1.y = acc[5][b]; v1.z = acc[6][b]; v1.w = acc[7][b];
      *(float4*)(&sP[s2][b][8*o2    ]) = v0;
      *(float4*)(&sP[s2][b][8*o2 + 4]) = v1;
    }
  }
  __syncthreads();

  // ========== Phase 2b: combine 4 k-quarters + LSTM nonlin (f-gate dropped) ====
  {
    const int j    = tid & 127;
    const int half = tid >> 7;           // 0,1 -> boxes {0,1},{2,3}
    const float bi = b_ih[j      ] + b_hh[j      ];
    const float bg = b_ih[j + 256] + b_hh[j + 256];
    const float bo = b_ih[j + 384] + b_hh[j + 384];
    #pragma unroll
    for (int bb = 0; bb < 2; ++bb) {
      const int b = half * 2 + bb;
      const float ai = sP[0][b][j      ] + sP[1][b][j      ] + sP[2][b][j      ] + sP[3][b][j      ] + bi;
      const float ag = sP[0][b][128 + j] + sP[1][b][128 + j] + sP[2][b][128 + j] + sP[3][b][128 + j] + bg;
      const float ao = sP[0][b][256 + j] + sP[1][b][256 + j] + sP[2][b][256 + j] + sP[3][b][256 + j] + bo;
      const float c  = fsig(ai) * ftanh(ag);
      h_lds[b][j] = fsig(ao) * ftanh(c);
    }
  }
  __syncthreads();   // h ready; sP free for reuse

  // ========== Phase 3: head hidden. Thread = (row-OCTET o3<24, k-8th s3<8) =====
  if (tid < 192) {
    const int k0 = s3 * 16;
    float acc[8][BPB];
    #pragma unroll
    for (int j = 0; j < 8; ++j)
      #pragma unroll
      for (int b = 0; b < BPB; ++b) acc[j][b] = 0.f;
    #pragma unroll
    for (int k4 = 0; k4 < 4; ++k4) {
      const int kb = k0 + 4*k4;
      uint4 W[4];
      if (k4 == 0) {
        #pragma unroll
        for (int kk = 0; kk < 4; ++kk) W[kk] = Wpre3[kk];
      } else {
        #pragma unroll
        for (int kk = 0; kk < 4; ++kk)
          W[kk] = *(const uint4*)(wt_h2 + ((size_t)(kb + kk) * 192 + 8*o3) / 2);
      }
      float4 hv[BPB];
      #pragma unroll
      for (int b = 0; b < BPB; ++b) hv[b] = *(const float4*)(&h_lds[b][kb]);  // broadcast
      #pragma unroll
      for (int kk = 0; kk < 4; ++kk) {
        const float w0 = bf_lo(W[kk].x), w1 = bf_hi(W[kk].x);
        const float w2 = bf_lo(W[kk].y), w3 = bf_hi(W[kk].y);
        const float w4 = bf_lo(W[kk].z), w5 = bf_hi(W[kk].z);
        const float w6 = bf_lo(W[kk].w), w7 = bf_hi(W[kk].w);
        #pragma unroll
        for (int b = 0; b < BPB; ++b) {
          const float hc = (kk == 0) ? hv[b].x : (kk == 1) ? hv[b].y : (kk == 2) ? hv[b].z : hv[b].w;
          acc[0][b] = fmaf(w0, hc, acc[0][b]);
          acc[1][b] = fmaf(w1, hc, acc[1][b]);
          acc[2][b] = fmaf(w2, hc, acc[2][b]);
          acc[3][b] = fmaf(w3, hc, acc[3][b]);
          acc[4][b] = fmaf(w4, hc, acc[4][b]);
          acc[5][b] = fmaf(w5, hc, acc[5][b]);
          acc[6][b] = fmaf(w6, hc, acc[6][b]);
          acc[7][b] = fmaf(w7, hc, acc[7][b]);
        }
      }
    }
    const int buf = s3 >> 1;
    const int off = (s3 & 1) * 192;
    #pragma unroll
    for (int b = 0; b < BPB; ++b) {
      float4 v0; v0.x = acc[0][b]; v0.y = acc[1][b]; v0.z = acc[2][b]; v0.w = acc[3][b];
      float4 v1; v1.x = acc[4][b]; v1.y = acc[5][b]; v1.z = acc[6][b]; v1.w = acc[7][b];
      *(float4*)(&sP[buf][b][off + 8*o3    ]) = v0;
      *(float4*)(&sP[buf][b][off + 8*o3 + 4]) = v1;
    }
  }
  __syncthreads();

  // ========== Phase 3b: combine 8 k-eighths + bias + relu -> u_lds =============
  {
    #pragma unroll
    for (int i = 0; i < 3; ++i) {
      const int idx = tid + 256 * i;     // 768 = 4 boxes x 192 rows
      const int b = idx / 192;
      const int r = idx - b * 192;
      const int head = r >> 6, brow = r & 63;
      const float bias = ((head == 0) ? b_p1 : (head == 1) ? b_s1 : b_c1)[brow];
      float v = bias;
      #pragma unroll
      for (int p = 0; p < 8; ++p) v += sP[p >> 1][b][(p & 1) * 192 + r];
      u_lds[head * BPB + b][brow] = fmaxf(v, 0.f);
    }
  }
  __syncthreads();

  // ========== Phase 4: head output layers (4 boxes x 5 outputs = 20 threads) ==
  if (tid < BPB * 5) {
    const int b = tid / 5, o = tid % 5;
    const int head = (o < 2) ? 0 : (o < 4) ? 1 : 2;
    const float* W2; float bias;
    if      (o == 0) { W2 = W_p2;      bias = b_p2[0]; }
    else if (o == 1) { W2 = W_p2 + 64; bias = b_p2[1]; }
    else if (o == 2) { W2 = W_s2;      bias = b_s2[0]; }
    else if (o == 3) { W2 = W_s2 + 64; bias = b_s2[1]; }
    else             { W2 = W_c2;      bias = b_c2[0]; }
    const float* ur = u_lds[head * BPB + b];
    float a0 = bias, a1 = 0.f, a2 = 0.f, a3 = 0.f;
    #pragma unroll 4
    for (int k = 0; k < 64; k += 4) {
      a0 = fmaf(ur[k  ], W2[k  ], a0);
      a1 = fmaf(ur[k+1], W2[k+1], a1);
      a2 = fmaf(ur[k+2], W2[k+2], a2);
      a3 = fmaf(ur[k+3], W2[k+3], a3);
    }
    res_lds[b][o] = (a0 + a1) + (a2 + a3);
  }
  __syncthreads();

  // ========== Phase 5: box decode + write =====================================
  if (tid < BPB) {
    const int gb = base + tid;
    if (gb < N) {
      const float4 bx = ((const float4*)boxes)[gb];
      const float cx = (bx.x + bx.z) * 0.5f;
      const float cy = (bx.y + bx.w) * 0.5f;
      const float w  = bx.z - bx.x;
      const float hh = bx.w - bx.y;
      const float ncx = cx + res_lds[tid][0];
      const float ncy = cy + res_lds[tid][1];
      const float nw  = w  * __expf(res_lds[tid][2]);
      const float nh  = hh * __expf(res_lds[tid][3]);
      const float cf  = fsig(res_lds[tid][4]);
      float* op = out + (size_t)gb * 5;
      op[0] = ncx - nw * 0.5f;
      op[1] = ncy - nh * 0.5f;
      op[2] = ncx + nw * 0.5f;
      op[3] = ncy + nh * 0.5f;
      op[4] = cf;
    }
  }
}

extern "C" void kernel_launch(void* const* d_in, const int* in_sizes, int n_in,
                              void* d_out, int out_size, void* d_ws, size_t ws_size,
                              hipStream_t stream) {
  (void)n_in; (void)out_size; (void)ws_size;
  const float* mv       = (const float*)d_in[0];
  const float* boxes    = (const float*)d_in[1];
  const float* W_stats  = (const float*)d_in[2];
  const float* b_stats  = (const float*)d_in[3];
  const float* g_stats  = (const float*)d_in[4];
  const float* be_stats = (const float*)d_in[5];
  const float* W_b1     = (const float*)d_in[6];
  const float* b_b1     = (const float*)d_in[7];
  const float* g_b1     = (const float*)d_in[8];
  const float* be_b1    = (const float*)d_in[9];
  const float* W_b2     = (const float*)d_in[10];
  const float* b_b2     = (const float*)d_in[11];
  const float* g_b2     = (const float*)d_in[12];
  const float* be_b2    = (const float*)d_in[13];
  const float* W_ih     = (const float*)d_in[14];
  // d_in[15] = W_hh: unused (h0 == 0)
  const float* b_ih     = (const float*)d_in[16];
  const float* b_hh     = (const float*)d_in[17];
  const float* W_p1     = (const float*)d_in[18];
  const float* b_p1     = (const float*)d_in[19];
  const float* W_p2     = (const float*)d_in[20];
  const float* b_p2     = (const float*)d_in[21];
  const float* W_s1     = (const float*)d_in[22];
  const float* b_s1     = (const float*)d_in[23];
  const float* W_s2     = (const float*)d_in[24];
  const float* b_s2     = (const float*)d_in[25];
  const float* W_c1     = (const float*)d_in[26];
  const float* b_c1     = (const float*)d_in[27];
  const float* W_c2     = (const float*)d_in[28];
  const float* b_c2     = (const float*)d_in[29];

  unsigned int* wt_ih2 = (unsigned int*)d_ws;     // 18432 uints (73.7 KB)
  unsigned int* wt_h2  = wt_ih2 + 18432;          // 12288 uints (49.2 KB)

  transpose_kernel<<<120, 256, 0, stream>>>(W_ih, W_p1, W_s1, W_c1, wt_ih2, wt_h2);

  const int N = in_sizes[1] / 4;
  const int grid = (N + BPB - 1) / BPB;           // 1024 blocks: one round on 256 CUs
  tracker_kernel<<<grid, 256, 0, stream>>>(
      mv, boxes,
      W_stats, b_stats, g_stats, be_stats,
      W_b1, b_b1, g_b1, be_b1,
      W_b2, b_b2, g_b2, be_b2,
      wt_ih2, b_ih, b_hh,
      wt_h2,
      b_p1, W_p2, b_p2,
      b_s1, W_s2, b_s2,
      b_c1, W_c2, b_c2,
      (float*)d_out, N);
}

// Round 11
// 128.584 us; speedup vs baseline: 1.0718x; 1.0718x over previous
//
#include <hip/hip_runtime.h>
#include <math.h>

#define GRID_G 60
#define GRID_GG 3600
#define BPB 8

// ---------- width-32 butterfly reductions ----------
__device__ __forceinline__ float wred32sum(float v){
  #pragma unroll
  for (int m = 16; m; m >>= 1) v += __shfl_xor(v, m, 32);
  return v;
}
__device__ __forceinline__ float wred32max(float v){
  #pragma unroll
  for (int m = 16; m; m >>= 1) v = fmaxf(v, __shfl_xor(v, m, 32));
  return v;
}
__device__ __forceinline__ float wred32min(float v){
  #pragma unroll
  for (int m = 16; m; m >>= 1) v = fminf(v, __shfl_xor(v, m, 32));
  return v;
}
__device__ __forceinline__ float frcp(float x){ return __builtin_amdgcn_rcpf(x); }
__device__ __forceinline__ float fsig(float x){ return frcp(1.0f + __expf(-x)); }
__device__ __forceinline__ float ftanh(float x){ return 1.0f - 2.0f*frcp(1.0f + __expf(2.0f*x)); }

// ---------- kernel 1: weight transpose to K-major (4 outputs/thread) ----------
// wt_ih[k*384 + r'] = W_ih[row(r')*96 + k], row(r') = r'<128 ? r' : r'+128
// wt_h [k*192 + r''] = {W_p1|W_s1|W_c1}[(r''&63)*128 + k]
__global__ __launch_bounds__(256) void transpose_kernel(
    const float* __restrict__ W_ih,
    const float* __restrict__ W_p1, const float* __restrict__ W_s1,
    const float* __restrict__ W_c1,
    float* __restrict__ wt_ih, float* __restrict__ wt_h)
{
  const int i4 = blockIdx.x * 256 + threadIdx.x;
  if (i4 < 9216) {                       // 96*384/4 quads
    const int e = i4 * 4;
    const int k = e / 384, r0 = e % 384;
    float4 v;
    { const int r = r0;     const int row = (r < 128) ? r : r + 128; v.x = W_ih[row*96 + k]; }
    { const int r = r0 + 1; const int row = (r < 128) ? r : r + 128; v.y = W_ih[row*96 + k]; }
    { const int r = r0 + 2; const int row = (r < 128) ? r : r + 128; v.z = W_ih[row*96 + k]; }
    { const int r = r0 + 3; const int row = (r < 128) ? r : r + 128; v.w = W_ih[row*96 + k]; }
    ((float4*)wt_ih)[i4] = v;
  } else if (i4 < 9216 + 6144) {         // 128*192/4 quads
    const int j4 = i4 - 9216;
    const int e = j4 * 4;
    const int k = e / 192, r0 = e % 192;
    const float* W = (r0 < 64) ? W_p1 : (r0 < 128) ? W_s1 : W_c1;
    float4 v;
    v.x = W[((r0    ) & 63) * 128 + k];
    v.y = W[((r0 + 1) & 63) * 128 + k];
    v.z = W[((r0 + 2) & 63) * 128 + k];
    v.w = W[((r0 + 3) & 63) * 128 + k];
    ((float4*)wt_h)[j4] = v;
  }
}

// ---------- kernel 2: fused tracker; K-split GEMV => each weight read ONCE/block
__global__ __launch_bounds__(256) void tracker_kernel(
    const float* __restrict__ mv,        // (2,60,60)
    const float* __restrict__ boxes,     // (N,4)
    const float* __restrict__ W_stats, const float* __restrict__ b_stats,
    const float* __restrict__ g_stats, const float* __restrict__ be_stats,
    const float* __restrict__ W_b1,  const float* __restrict__ b_b1,
    const float* __restrict__ g_b1,  const float* __restrict__ be_b1,
    const float* __restrict__ W_b2,  const float* __restrict__ b_b2,
    const float* __restrict__ g_b2,  const float* __restrict__ be_b2,
    const float* __restrict__ wt_ih, // K-major [96][384]
    const float* __restrict__ b_ih,  const float* __restrict__ b_hh,
    const float* __restrict__ wt_h,  // K-major [128][192]
    const float* __restrict__ b_p1,  const float* __restrict__ W_p2, const float* __restrict__ b_p2,
    const float* __restrict__ b_s1,  const float* __restrict__ W_s2, const float* __restrict__ b_s2,
    const float* __restrict__ b_c1,  const float* __restrict__ W_c2, const float* __restrict__ b_c2,
    float* __restrict__ out, int N)
{
  __shared__ __align__(16) float x_lds[BPB][96];   // [mv_feat(64) | box_feat(32)]
  __shared__ __align__(16) float sA[BPB][384];     // P2a partial (k-half 0) / P3 partials 0,1
  __shared__ __align__(16) float sB[BPB][384];     // P2a partial (k-half 1) / P3 partials 2,3
  __shared__ __align__(16) float h_lds[BPB][128];  // LSTM hidden
  __shared__ __align__(16) float h1_lds[BPB][32];
  __shared__ float u_lds[3*BPB][65];               // head hidden, +1 pad
  __shared__ float res_lds[BPB][5];

  const int tid  = threadIdx.x;
  const int base = blockIdx.x * BPB;

  // ========== Phase 1: one half-wave (32 lanes) per box, 8 boxes parallel ==
  {
    const int b   = tid >> 5;
    const int l32 = tid & 31;
    int gb = base + b; if (gb >= N) gb = N - 1;
    const float4 bx = ((const float4*)boxes)[gb];
    const float bn0 = fminf(fmaxf(bx.x * (1.0f/960.0f), 0.f), 1.f);
    const float bn1 = fminf(fmaxf(bx.y * (1.0f/960.0f), 0.f), 1.f);
    const float bn2 = fminf(fmaxf(bx.z * (1.0f/960.0f), 0.f), 1.f);
    const float bn3 = fminf(fmaxf(bx.w * (1.0f/960.0f), 0.f), 1.f);

    int x1 = (int)floorf(bn0 * 60.f); x1 = min(max(x1, 0), 59);
    int y1 = (int)floorf(bn1 * 60.f); y1 = min(max(y1, 0), 59);
    int x2 = (int)ceilf (bn2 * 60.f); x2 = min(max(x2, x1 + 1), 60);
    int y2 = (int)ceilf (bn3 * 60.f); y2 = min(max(y2, y1 + 1), 60);
    const int w = x2 - x1, hh = y2 - y1;
    const int cnt = w * hh;              // <= ~121
    const float rw = 1.0f / (float)w;

    float s0=0.f, s1=0.f, q0=0.f, q1=0.f;
    float hi0=-1e30f, hi1=-1e30f, lo0=1e30f, lo1=1e30f;
    for (int c = l32; c < cnt; c += 32) {
      const int yy = (int)(((float)c + 0.5f) * rw);   // exact floor(c/w) here
      const int xx = c - yy * w;
      const int idx = (y1 + yy) * GRID_G + (x1 + xx);
      const float m0 = mv[idx];
      const float m1 = mv[GRID_GG + idx];
      s0 += m0; q0 += m0*m0; hi0 = fmaxf(hi0, m0); lo0 = fminf(lo0, m0);
      s1 += m1; q1 += m1*m1; hi1 = fmaxf(hi1, m1); lo1 = fminf(lo1, m1);
    }
    s0 = wred32sum(s0); q0 = wred32sum(q0); hi0 = wred32max(hi0); lo0 = wred32min(lo0);
    s1 = wred32sum(s1); q1 = wred32sum(q1); hi1 = wred32max(hi1); lo1 = wred32min(lo1);
    const float inv = frcp((float)cnt);
    float st[6];
    st[0] = s0 * inv;
    st[1] = s1 * inv;
    st[2] = sqrtf(fmaxf(q0 * inv - st[0]*st[0], 0.f));
    st[3] = sqrtf(fmaxf(q1 * inv - st[1]*st[1], 0.f));
    st[4] = hi0 - lo0;
    st[5] = hi1 - lo1;

    // mv_feat (64) + LN + relu
    {
      const float* Wr0 = W_stats + l32 * 6;
      const float* Wr1 = W_stats + (l32 + 32) * 6;
      float v0 = b_stats[l32], v1 = b_stats[l32 + 32];
      #pragma unroll
      for (int k = 0; k < 6; ++k) { v0 = fmaf(st[k], Wr0[k], v0); v1 = fmaf(st[k], Wr1[k], v1); }
      const float mu  = wred32sum(v0 + v1) * (1.0f/64.0f);
      const float var = wred32sum(v0*v0 + v1*v1) * (1.0f/64.0f) - mu*mu;
      const float rs  = rsqrtf(var + 1e-5f);
      x_lds[b][l32     ] = fmaxf((v0-mu)*rs*g_stats[l32     ] + be_stats[l32     ], 0.f);
      x_lds[b][l32 + 32] = fmaxf((v1-mu)*rs*g_stats[l32 + 32] + be_stats[l32 + 32], 0.f);
    }

    // h1 (32) + LN + relu
    {
      const float* Wr = W_b1 + l32 * 4;
      const float v = b_b1[l32] + bn0*Wr[0] + bn1*Wr[1] + bn2*Wr[2] + bn3*Wr[3];
      const float mu  = wred32sum(v)   * (1.0f/32.0f);
      const float var = wred32sum(v*v) * (1.0f/32.0f) - mu*mu;
      h1_lds[b][l32] = fmaxf((v - mu) * rsqrtf(var + 1e-5f) * g_b1[l32] + be_b1[l32], 0.f);
    }
    __threadfence_block();   // same half-wave produces and consumes h1

    // box_feat (32) + LN + relu
    {
      const float* Wr = W_b2 + l32 * 32;
      float v = b_b2[l32];
      #pragma unroll
      for (int kk = 0; kk < 8; ++kk) {
        const float4 hv = *(const float4*)(&h1_lds[b][kk * 4]);  // broadcast
        const float4 wv = *(const float4*)(&Wr[kk * 4]);
        v = fmaf(wv.x,hv.x, fmaf(wv.y,hv.y, fmaf(wv.z,hv.z, fmaf(wv.w,hv.w, v))));
      }
      const float mu  = wred32sum(v)   * (1.0f/32.0f);
      const float var = wred32sum(v*v) * (1.0f/32.0f) - mu*mu;
      x_lds[b][64 + l32] = fmaxf((v - mu) * rsqrtf(var + 1e-5f) * g_b2[l32] + be_b2[l32], 0.f);
    }
  }
  __syncthreads();

  // ========== Phase 2a: gate pre-acts, K-SPLIT. Thread = (row-quad q, k-half s)
  // Each weight element is read by exactly ONE thread => wt_ih streamed once/block.
  if (tid < 192) {
    const int q = (tid < 96) ? tid : tid - 96;   // rows 4q..4q+3 (r'-space)
    const int s = (tid < 96) ? 0 : 1;            // k-half: k in [48s, 48s+48)
    float acc[4][BPB];
    #pragma unroll
    for (int j = 0; j < 4; ++j)
      #pragma unroll
      for (int b = 0; b < BPB; ++b) acc[j][b] = 0.f;
    const float4* WT = (const float4*)wt_ih;     // [k][96 quads]
    const int k0 = s * 48;
    #pragma unroll 2
    for (int k4 = 0; k4 < 12; ++k4) {
      const int kb = k0 + 4*k4;
      const float4 wv0 = WT[(size_t)(kb    ) * 96 + q];
      const float4 wv1 = WT[(size_t)(kb + 1) * 96 + q];
      const float4 wv2 = WT[(size_t)(kb + 2) * 96 + q];
      const float4 wv3 = WT[(size_t)(kb + 3) * 96 + q];
      #pragma unroll
      for (int b = 0; b < BPB; ++b) {
        const float4 xv = *(const float4*)(&x_lds[b][kb]);   // uniform addr: broadcast
        acc[0][b] = fmaf(wv0.x, xv.x, fmaf(wv1.x, xv.y, fmaf(wv2.x, xv.z, fmaf(wv3.x, xv.w, acc[0][b]))));
        acc[1][b] = fmaf(wv0.y, xv.x, fmaf(wv1.y, xv.y, fmaf(wv2.y, xv.z, fmaf(wv3.y, xv.w, acc[1][b]))));
        acc[2][b] = fmaf(wv0.z, xv.x, fmaf(wv1.z, xv.y, fmaf(wv2.z, xv.z, fmaf(wv3.z, xv.w, acc[2][b]))));
        acc[3][b] = fmaf(wv0.w, xv.x, fmaf(wv1.w, xv.y, fmaf(wv2.w, xv.z, fmaf(wv3.w, xv.w, acc[3][b]))));
      }
    }
    float* dst = (s == 0) ? &sA[0][0] : &sB[0][0];
    #pragma unroll
    for (int b = 0; b < BPB; ++b) {
      float4 v; v.x = acc[0][b]; v.y = acc[1][b]; v.z = acc[2][b]; v.w = acc[3][b];
      *(float4*)(dst + b * 384 + 4 * q) = v;
    }
  }
  __syncthreads();

  // ========== Phase 2b: combine k-halves + LSTM nonlinearity (f-gate dropped) ==
  {
    const int j    = tid & 127;
    const int half = tid >> 7;
    const float bi = b_ih[j      ] + b_hh[j      ];
    const float bg = b_ih[j + 256] + b_hh[j + 256];
    const float bo = b_ih[j + 384] + b_hh[j + 384];
    #pragma unroll
    for (int bb = 0; bb < 4; ++bb) {
      const int b = half * 4 + bb;
      const float ai = sA[b][j      ] + sB[b][j      ] + bi;
      const float ag = sA[b][128 + j] + sB[b][128 + j] + bg;
      const float ao = sA[b][256 + j] + sB[b][256 + j] + bo;
      const float c  = fsig(ai) * ftanh(ag);
      h_lds[b][j] = fsig(ao) * ftanh(c);
    }
  }
  __syncthreads();   // h ready; sA/sB free for reuse

  // ========== Phase 3: head hidden, K-SPLIT x4. Thread = (row-quad q48, k-qtr s4)
  // wt_h streamed once/block. Partials: s4 0,1 -> sA[b][{0,192}+r], 2,3 -> sB.
  if (tid < 192) {
    const int q48 = tid % 48;            // rows 4q48..4q48+3 (r''-space, 192 rows)
    const int s4  = tid / 48;            // k-quarter: k in [32*s4, 32*s4+32)
    float acc[4][BPB];
    #pragma unroll
    for (int j = 0; j < 4; ++j)
      #pragma unroll
      for (int b = 0; b < BPB; ++b) acc[j][b] = 0.f;
    const float4* WT = (const float4*)wt_h;      // [k][48 quads]
    const int k0 = s4 * 32;
    #pragma unroll 2
    for (int k4 = 0; k4 < 8; ++k4) {
      const int kb = k0 + 4*k4;
      const float4 wv0 = WT[(size_t)(kb    ) * 48 + q48];
      const float4 wv1 = WT[(size_t)(kb + 1) * 48 + q48];
      const float4 wv2 = WT[(size_t)(kb + 2) * 48 + q48];
      const float4 wv3 = WT[(size_t)(kb + 3) * 48 + q48];
      #pragma unroll
      for (int b = 0; b < BPB; ++b) {
        const float4 hv = *(const float4*)(&h_lds[b][kb]);   // uniform addr: broadcast
        acc[0][b] = fmaf(wv0.x, hv.x, fmaf(wv1.x, hv.y, fmaf(wv2.x, hv.z, fmaf(wv3.x, hv.w, acc[0][b]))));
        acc[1][b] = fmaf(wv0.y, hv.x, fmaf(wv1.y, hv.y, fmaf(wv2.y, hv.z, fmaf(wv3.y, hv.w, acc[1][b]))));
        acc[2][b] = fmaf(wv0.z, hv.x, fmaf(wv1.z, hv.y, fmaf(wv2.z, hv.z, fmaf(wv3.z, hv.w, acc[2][b]))));
        acc[3][b] = fmaf(wv0.w, hv.x, fmaf(wv1.w, hv.y, fmaf(wv2.w, hv.z, fmaf(wv3.w, hv.w, acc[3][b]))));
      }
    }
    float* dst = (s4 < 2) ? &sA[0][0] : &sB[0][0];
    const int off = (s4 & 1) * 192;
    #pragma unroll
    for (int b = 0; b < BPB; ++b) {
      float4 v; v.x = acc[0][b]; v.y = acc[1][b]; v.z = acc[2][b]; v.w = acc[3][b];
      *(float4*)(dst + b * 384 + off + 4 * q48) = v;
    }
  }
  __syncthreads();

  // ========== Phase 3b: combine k-quarters + bias + relu -> u_lds ==============
  {
    #pragma unroll
    for (int i = 0; i < 6; ++i) {
      const int idx = tid + 256 * i;     // 1536 = 8 boxes x 192 rows
      const int b = idx / 192;
      const int r = idx - b * 192;
      const int head = r >> 6, brow = r & 63;
      const float bias = ((head == 0) ? b_p1 : (head == 1) ? b_s1 : b_c1)[brow];
      const float v = sA[b][r] + sA[b][192 + r] + sB[b][r] + sB[b][192 + r] + bias;
      u_lds[head * BPB + b][brow] = fmaxf(v, 0.f);
    }
  }
  __syncthreads();

  // ========== Phase 4: head output layers (8 boxes x 5 outputs = 40 threads) ==
  if (tid < BPB * 5) {
    const int b = tid / 5, o = tid % 5;
    const int head = (o < 2) ? 0 : (o < 4) ? 1 : 2;
    const float* W2; float bias;
    if      (o == 0) { W2 = W_p2;      bias = b_p2[0]; }
    else if (o == 1) { W2 = W_p2 + 64; bias = b_p2[1]; }
    else if (o == 2) { W2 = W_s2;      bias = b_s2[0]; }
    else if (o == 3) { W2 = W_s2 + 64; bias = b_s2[1]; }
    else             { W2 = W_c2;      bias = b_c2[0]; }
    const float* ur = u_lds[head * BPB + b];
    float a0 = bias, a1 = 0.f, a2 = 0.f, a3 = 0.f;
    #pragma unroll 4
    for (int k = 0; k < 64; k += 4) {
      a0 = fmaf(ur[k  ], W2[k  ], a0);
      a1 = fmaf(ur[k+1], W2[k+1], a1);
      a2 = fmaf(ur[k+2], W2[k+2], a2);
      a3 = fmaf(ur[k+3], W2[k+3], a3);
    }
    res_lds[b][o] = (a0 + a1) + (a2 + a3);
  }
  __syncthreads();

  // ========== Phase 5: box decode + write =====================================
  if (tid < BPB) {
    const int gb = base + tid;
    if (gb < N) {
      const float4 bx = ((const float4*)boxes)[gb];
      const float cx = (bx.x + bx.z) * 0.5f;
      const float cy = (bx.y + bx.w) * 0.5f;
      const float w  = bx.z - bx.x;
      const float hh = bx.w - bx.y;
      const float ncx = cx + res_lds[tid][0];
      const float ncy = cy + res_lds[tid][1];
      const float nw  = w  * __expf(res_lds[tid][2]);
      const float nh  = hh * __expf(res_lds[tid][3]);
      const float cf  = fsig(res_lds[tid][4]);
      float* op = out + (size_t)gb * 5;
      op[0] = ncx - nw * 0.5f;
      op[1] = ncy - nh * 0.5f;
      op[2] = ncx + nw * 0.5f;
      op[3] = ncy + nh * 0.5f;
      op[4] = cf;
    }
  }
}

extern "C" void kernel_launch(void* const* d_in, const int* in_sizes, int n_in,
                              void* d_out, int out_size, void* d_ws, size_t ws_size,
                              hipStream_t stream) {
  (void)n_in; (void)out_size; (void)ws_size;
  const float* mv       = (const float*)d_in[0];
  const float* boxes    = (const float*)d_in[1];
  const float* W_stats  = (const float*)d_in[2];
  const float* b_stats  = (const float*)d_in[3];
  const float* g_stats  = (const float*)d_in[4];
  const float* be_stats = (const float*)d_in[5];
  const float* W_b1     = (const float*)d_in[6];
  const float* b_b1     = (const float*)d_in[7];
  const float* g_b1     = (const float*)d_in[8];
  const float* be_b1    = (const float*)d_in[9];
  const float* W_b2     = (const float*)d_in[10];
  const float* b_b2     = (const float*)d_in[11];
  const float* g_b2     = (const float*)d_in[12];
  const float* be_b2    = (const float*)d_in[13];
  const float* W_ih     = (const float*)d_in[14];
  // d_in[15] = W_hh: unused (h0 == 0)
  const float* b_ih     = (const float*)d_in[16];
  const float* b_hh     = (const float*)d_in[17];
  const float* W_p1     = (const float*)d_in[18];
  const float* b_p1     = (const float*)d_in[19];
  const float* W_p2     = (const float*)d_in[20];
  const float* b_p2     = (const float*)d_in[21];
  const float* W_s1     = (const float*)d_in[22];
  const float* b_s1     = (const float*)d_in[23];
  const float* W_s2     = (const float*)d_in[24];
  const float* b_s2     = (const float*)d_in[25];
  const float* W_c1     = (const float*)d_in[26];
  const float* b_c1     = (const float*)d_in[27];
  const float* W_c2     = (const float*)d_in[28];
  const float* b_c2     = (const float*)d_in[29];

  float* wt_ih = (float*)d_ws;            // 96*384 floats
  float* wt_h  = wt_ih + 96 * 384;        // 128*192 floats (total ~246 KB)

  transpose_kernel<<<60, 256, 0, stream>>>(W_ih, W_p1, W_s1, W_c1, wt_ih, wt_h);

  const int N = in_sizes[1] / 4;
  const int grid = (N + BPB - 1) / BPB;
  tracker_kernel<<<grid, 256, 0, stream>>>(
      mv, boxes,
      W_stats, b_stats, g_stats, be_stats,
      W_b1, b_b1, g_b1, be_b1,
      W_b2, b_b2, g_b2, be_b2,
      wt_ih, b_ih, b_hh,
      wt_h,
      b_p1, W_p2, b_p2,
      b_s1, W_s2, b_s2,
      b_c1, W_c2, b_c2,
      (float*)d_out, N);
}